// Round 4
// baseline (568.142 us; speedup 1.0000x reference)
//
#include <hip/hip_runtime.h>
#include <math.h>

#define NN 50000
#define NE 1600000
#define DF 256
#define NBUCK 391   // ceil(NN/128); bucket = dst >> 7

typedef unsigned short ushortT;
typedef __attribute__((ext_vector_type(8))) short short8;
typedef __attribute__((ext_vector_type(4))) float floatx4;

__device__ __forceinline__ unsigned bf16rne(float f) {
    unsigned u = __float_as_uint(f);
    return (u + 0x7fffu + ((u >> 16) & 1u)) >> 16;
}

#define ASYNC16(gptr, ldsptr) \
    __builtin_amdgcn_global_load_lds((const __attribute__((address_space(1))) unsigned*)(gptr), \
                                     (__attribute__((address_space(3))) unsigned*)(ldsptr), 16, 0, 0)

// ---------------- CSR build via bucket binning ----------------

__global__ void k_zero(int* __restrict__ bcnt) {
    int i = blockIdx.x * 256 + threadIdx.x;
    if (i < NBUCK) bcnt[i] = 0;
}

__global__ __launch_bounds__(256)
void k_bhist(const int* __restrict__ dst, int* __restrict__ bcnt) {
    __shared__ int h[NBUCK];
    for (int i = threadIdx.x; i < NBUCK; i += 256) h[i] = 0;
    __syncthreads();
    int base = blockIdx.x * 4096;
#pragma unroll
    for (int i = 0; i < 16; ++i) {
        int e = base + i * 256 + threadIdx.x;
        if (e < NE) atomicAdd(&h[dst[e] >> 7], 1);
    }
    __syncthreads();
    for (int i = threadIdx.x; i < NBUCK; i += 256)
        if (h[i]) atomicAdd(&bcnt[i], h[i]);
}

__global__ void k_bscan(const int* __restrict__ bcnt, int* __restrict__ bbase,
                        int* __restrict__ cursor, int* __restrict__ row_ptr,
                        float* __restrict__ nrm) {
    __shared__ int s[512];
    int t = threadIdx.x;
    int v = (t < NBUCK) ? bcnt[t] : 0;
    s[t] = v; __syncthreads();
    for (int off = 1; off < 512; off <<= 1) {
        int x = (t >= off) ? s[t - off] : 0;
        __syncthreads();
        s[t] += x;
        __syncthreads();
    }
    if (t < NBUCK) { bbase[t] = s[t] - v; cursor[t] = s[t] - v; }
    if (t == 0) { bbase[NBUCK] = NE; row_ptr[NN] = NE; *nrm = 0.0f; }
}

__global__ __launch_bounds__(256)
void k_bin(const int* __restrict__ src, const int* __restrict__ dst,
           int* __restrict__ cursor, unsigned* __restrict__ rec) {
    __shared__ int h[NBUCK];
    __shared__ int gb[NBUCK];
    for (int i = threadIdx.x; i < NBUCK; i += 256) h[i] = 0;
    __syncthreads();
    const int base = blockIdx.x * 2048;
    int bk[8], rk[8];
    unsigned pk[8];
#pragma unroll
    for (int i = 0; i < 8; ++i) {
        int e = base + i * 256 + threadIdx.x;
        if (e < NE) {
            int d = dst[e];
            bk[i] = d >> 7;
            pk[i] = (unsigned)src[e] | ((unsigned)(d & 127) << 16);
            rk[i] = atomicAdd(&h[bk[i]], 1);
        } else bk[i] = -1;
    }
    __syncthreads();
    for (int i = threadIdx.x; i < NBUCK; i += 256) {
        int c = h[i];
        gb[i] = c ? atomicAdd(&cursor[i], c) : 0;
    }
    __syncthreads();
#pragma unroll
    for (int i = 0; i < 8; ++i)
        if (bk[i] >= 0) rec[gb[bk[i]] + rk[i]] = pk[i];
}

__global__ __launch_bounds__(256)
void k_csr(const unsigned* __restrict__ rec, const int* __restrict__ bbase,
           int* __restrict__ row_ptr, ushortT* __restrict__ csr) {
    __shared__ int cnt[128];
    __shared__ int cur[128];
    __shared__ int s[256];
    const int B = blockIdx.x, t = threadIdx.x;
    if (t < 128) cnt[t] = 0;
    __syncthreads();
    const int beg = bbase[B], end = bbase[B + 1];
    for (int p = beg + t; p < end; p += 256)
        atomicAdd(&cnt[(rec[p] >> 16) & 127], 1);
    __syncthreads();
    int v = (t < 128) ? cnt[t] : 0;
    s[t] = v; __syncthreads();
    for (int off = 1; off < 256; off <<= 1) {
        int x = (t >= off) ? s[t - off] : 0;
        __syncthreads();
        s[t] += x;
        __syncthreads();
    }
    if (t < 128) {
        int ex = s[t] - v;
        cur[t] = ex;
        int node = B * 128 + t;
        if (node < NN) row_ptr[node] = beg + ex;
    }
    __syncthreads();
    for (int p = beg + t; p < end; p += 256) {
        unsigned r = rec[p];
        int loc = atomicAdd(&cur[(r >> 16) & 127], 1);
        csr[beg + loc] = (ushortT)r;
    }
}

// ---------------- conversions ----------------

__global__ __launch_bounds__(256)
void k_cvt_emb(const float* __restrict__ emb, const int* __restrict__ gather,
               ushortT* __restrict__ out) {
    long long i = ((long long)blockIdx.x * 256 + threadIdx.x) * 8;
    int row = (int)(i >> 8);
    int col = (int)(i & 255);
    long long g = (long long)gather[row] * 256 + col;
    float4 v0 = *(const float4*)(emb + g);
    float4 v1 = *(const float4*)(emb + g + 4);
    uint4 o;
    o.x = bf16rne(v0.x) | (bf16rne(v0.y) << 16);
    o.y = bf16rne(v0.z) | (bf16rne(v0.w) << 16);
    o.z = bf16rne(v1.x) | (bf16rne(v1.y) << 16);
    o.w = bf16rne(v1.z) | (bf16rne(v1.w) << 16);
    *(uint4*)(out + i) = o;
}

__global__ __launch_bounds__(256)
void k_cvt_w(const float* __restrict__ Ws, const float* __restrict__ Wn,
             ushortT* __restrict__ Wt) {
    int idx = blockIdx.x * 256 + threadIdx.x;
    int n = idx >> 9;
    int k = idx & 511;
    float v = (k < 256) ? Ws[k * 256 + n] : Wn[(k - 256) * 256 + n];
    Wt[idx] = (ushortT)bf16rne(v);
}

// ---------------- fused agg + dual GEMM ----------------
// block = bucket of 128 dst nodes. Phase 1: mean-aggregate neighbor rows into
// LDS (k-tiled layout matching MFMA A-frag reads). Phase 2: C = [A|agg]@Wt + b
// with neigh-K served from LDS, self-K + W via global_load_lds. Two n-passes.
// LDS: Aneigh 64K + As 8K + Bs 8K = 81920 B -> exactly 2 blocks/CU.

template<int RELU, int NORM>
__global__ __launch_bounds__(256, 2)
void k_fused(const ushortT* __restrict__ A, const ushortT* __restrict__ Wt,
             const float* __restrict__ bias, const int* __restrict__ row_ptr,
             const ushortT* __restrict__ csr,
             ushortT* __restrict__ Cb, float* __restrict__ Cf,
             float* __restrict__ norm_acc) {
    __shared__ ushortT S[40960];   // [0,32768) Aneigh ktiles, [32768,36864) As, [36864,40960) Bs

    const int t = threadIdx.x;
    const int w = t >> 6;
    const int lane = t & 63;
    const int half = lane >> 5;
    const int l5 = lane & 31;
    const int m0 = blockIdx.x * 128;

    // ---- phase 1: aggregate 32 nodes per wave into LDS ----
    for (int i = 0; i < 32; ++i) {
        const int nl = w * 32 + i;
        const int node = m0 + nl;
        if (node >= NN) break;
        const int beg = row_ptr[node], end = row_ptr[node + 1];
        float s[8] = {0.f, 0.f, 0.f, 0.f, 0.f, 0.f, 0.f, 0.f};
        int p = beg + half;
#define ACCUM(q) do { \
        s[0] += __uint_as_float(q.x << 16); \
        s[1] += __uint_as_float(q.x & 0xffff0000u); \
        s[2] += __uint_as_float(q.y << 16); \
        s[3] += __uint_as_float(q.y & 0xffff0000u); \
        s[4] += __uint_as_float(q.z << 16); \
        s[5] += __uint_as_float(q.z & 0xffff0000u); \
        s[6] += __uint_as_float(q.w << 16); \
        s[7] += __uint_as_float(q.w & 0xffff0000u); \
    } while (0)
        for (; p + 6 < end; p += 8) {
            long long r0 = (long long)csr[p]     * 256 + l5 * 8;
            long long r1 = (long long)csr[p + 2] * 256 + l5 * 8;
            long long r2 = (long long)csr[p + 4] * 256 + l5 * 8;
            long long r3 = (long long)csr[p + 6] * 256 + l5 * 8;
            uint4 a = *(const uint4*)(A + r0);
            uint4 b = *(const uint4*)(A + r1);
            uint4 c = *(const uint4*)(A + r2);
            uint4 d = *(const uint4*)(A + r3);
            ACCUM(a); ACCUM(b); ACCUM(c); ACCUM(d);
        }
        for (; p < end; p += 2) {
            long long r0 = (long long)csr[p] * 256 + l5 * 8;
            uint4 a = *(const uint4*)(A + r0);
            ACCUM(a);
        }
#undef ACCUM
#pragma unroll
        for (int k = 0; k < 8; ++k) s[k] += __shfl_down(s[k], 32);
        if (half == 0) {
            const float inv = 1.0f / fmaxf((float)(end - beg), 1.0f);
            uint4 o;
            o.x = bf16rne(s[0] * inv) | (bf16rne(s[1] * inv) << 16);
            o.y = bf16rne(s[2] * inv) | (bf16rne(s[3] * inv) << 16);
            o.z = bf16rne(s[4] * inv) | (bf16rne(s[5] * inv) << 16);
            o.w = bf16rne(s[6] * inv) | (bf16rne(s[7] * inv) << 16);
            // ktile = l5>>2, within-tile k = (l5&3)*8, row = nl
            *(uint4*)&S[(l5 >> 2) * 4096 + nl * 32 + (l5 & 3) * 8] = o;
        }
    }
    __syncthreads();

    // ---- phase 2: dual GEMM, two n-passes ----
    const int r0 = t >> 2;
    const int cu = (t & 3) * 8;
    const long long gA0 = (long long)min(m0 + r0, NN - 1) * 256;
    const long long gA1 = (long long)min(m0 + r0 + 64, NN - 1) * 256;

    const unsigned lA0 = 32768 + w * 512;
    const unsigned lA1 = 32768 + 2048 + w * 512;
    const unsigned lB0 = 36864 + w * 512;
    const unsigned lB1 = 36864 + 2048 + w * 512;

    const int wm = w & 1, wn = w >> 1;
    const int fm = lane & 15;
    const int fk = (lane >> 4) * 8;

    float sumsq = 0.0f;

    for (int np = 0; np < 2; ++np) {
        const int n0 = np * 128;
        const int gB0 = (n0 + r0) * 512;
        const int gB1 = (n0 + r0 + 64) * 512;

        floatx4 acc[4][4];
#pragma unroll
        for (int i = 0; i < 4; ++i)
#pragma unroll
            for (int j = 0; j < 4; ++j) acc[i][j] = (floatx4){0.f, 0.f, 0.f, 0.f};

        for (int kt = 0; kt < 512; kt += 32) {
            const bool self = kt < 256;
            __syncthreads();
            if (self) {
                ASYNC16(A + gA0 + kt + cu, S + lA0);
                ASYNC16(A + gA1 + kt + cu, S + lA1);
            }
            ASYNC16(Wt + gB0 + kt + cu, S + lB0);
            ASYNC16(Wt + gB1 + kt + cu, S + lB1);
            __syncthreads();

            short8 af[4], bf[4];
            if (self) {
#pragma unroll
                for (int i = 0; i < 4; ++i)
                    af[i] = *(const short8*)&S[32768 + (wm * 64 + i * 16 + fm) * 32 + fk];
            } else {
                const int kb = (kt - 256) >> 5;
#pragma unroll
                for (int i = 0; i < 4; ++i)
                    af[i] = *(const short8*)&S[kb * 4096 + (wm * 64 + i * 16 + fm) * 32 + fk];
            }
#pragma unroll
            for (int j = 0; j < 4; ++j)
                bf[j] = *(const short8*)&S[36864 + (wn * 64 + j * 16 + fm) * 32 + fk];
#pragma unroll
            for (int i = 0; i < 4; ++i)
#pragma unroll
                for (int j = 0; j < 4; ++j)
                    acc[i][j] = __builtin_amdgcn_mfma_f32_16x16x32_bf16(af[i], bf[j], acc[i][j], 0, 0, 0);
        }

        float bj[4];
#pragma unroll
        for (int j = 0; j < 4; ++j) bj[j] = bias[n0 + wn * 64 + j * 16 + fm];

#pragma unroll
        for (int i = 0; i < 4; ++i) {
#pragma unroll
            for (int r = 0; r < 4; ++r) {
                const int row = m0 + wm * 64 + i * 16 + (lane >> 4) * 4 + r;
                if (row < NN) {
#pragma unroll
                    for (int j = 0; j < 4; ++j) {
                        const int col = n0 + wn * 64 + j * 16 + fm;
                        float v = acc[i][j][r] + bj[j];
                        if (RELU) v = fmaxf(v, 0.0f);
                        if (NORM) {
                            Cf[(long long)row * 256 + col] = v;
                            sumsq += v * v;
                        } else {
                            Cb[(long long)row * 256 + col] = (ushortT)bf16rne(v);
                        }
                    }
                }
            }
        }
    }

    if (NORM) {
#pragma unroll
        for (int off = 32; off > 0; off >>= 1) sumsq += __shfl_down(sumsq, off);
        __syncthreads();              // As region no longer needed
        float* red = (float*)&S[32768];
        if (lane == 0) red[w] = sumsq;
        __syncthreads();
        if (t == 0) atomicAdd(norm_acc, red[0] + red[1] + red[2] + red[3]);
    }
}

__global__ void k_scale(float* __restrict__ out, const float* __restrict__ nrm) {
    const float s = 1.0f / sqrtf(*nrm);
    long long i = ((long long)blockIdx.x * 256 + threadIdx.x) * 4;
    float4 v = *(float4*)&out[i];
    v.x *= s; v.y *= s; v.z *= s; v.w *= s;
    *(float4*)&out[i] = v;
}

// ---------------- launch ----------------

extern "C" void kernel_launch(void* const* d_in, const int* in_sizes, int n_in,
                              void* d_out, int out_size, void* d_ws, size_t ws_size,
                              hipStream_t stream) {
    const int*   input_nodes = (const int*)d_in[0];
    const int*   esrc = (const int*)d_in[1];
    const int*   edst = (const int*)d_in[2];
    const float* emb  = (const float*)d_in[3];
    const float* Ws0  = (const float*)d_in[4];
    const float* Wn0  = (const float*)d_in[5];
    const float* b0   = (const float*)d_in[6];
    const float* Ws1  = (const float*)d_in[7];
    const float* Wn1  = (const float*)d_in[8];
    const float* b1   = (const float*)d_in[9];
    float* out = (float*)d_out;

    char* base = (char*)d_ws;
    ushortT*  embb    = (ushortT*) (base);                  // 25,600,000
    ushortT*  h1b     = (ushortT*) (base + 25600000);       // 25,600,000
    unsigned* rec     = (unsigned*)(base + 51200000);       //  6,400,000
    ushortT*  csr     = (ushortT*) (base + 57600000);       //  3,200,000
    ushortT*  Wt0     = (ushortT*) (base + 60800000);       //    262,144
    ushortT*  Wt1     = (ushortT*) (base + 61062144);       //    262,144
    int*      row_ptr = (int*)     (base + 61324288);       //    200,016
    int*      bcnt    = (int*)     (base + 61524304);       //      1,600
    int*      bbase   = (int*)     (base + 61525904);       //      1,600
    int*      cursor  = (int*)     (base + 61527504);       //      1,600
    float*    nrm     = (float*)   (base + 61529104);       //          4

    k_zero  <<<2,     256, 0, stream>>>(bcnt);
    k_bhist <<<391,   256, 0, stream>>>(edst, bcnt);
    k_bscan <<<1,     512, 0, stream>>>(bcnt, bbase, cursor, row_ptr, nrm);
    k_bin   <<<782,   256, 0, stream>>>(esrc, edst, cursor, rec);
    k_csr   <<<NBUCK, 256, 0, stream>>>(rec, bbase, row_ptr, csr);

    k_cvt_emb<<<NN * DF / 8 / 256, 256, 0, stream>>>(emb, input_nodes, embb);
    k_cvt_w  <<<512, 256, 0, stream>>>(Ws0, Wn0, Wt0);
    k_cvt_w  <<<512, 256, 0, stream>>>(Ws1, Wn1, Wt1);

    // layer 0 (fused agg + GEMM + relu -> bf16)
    k_fused<1, 0><<<NBUCK, 256, 0, stream>>>(embb, Wt0, b0, row_ptr, csr, h1b, nullptr, nullptr);
    // layer 1 (fused agg + GEMM + sumsq -> fp32)
    k_fused<0, 1><<<NBUCK, 256, 0, stream>>>(h1b, Wt1, b1, row_ptr, csr, nullptr, out, nrm);

    k_scale<<<NN * DF / 4 / 256, 256, 0, stream>>>(out, nrm);
}

// Round 5
// 478.539 us; speedup vs baseline: 1.1872x; 1.1872x over previous
//
#include <hip/hip_runtime.h>
#include <math.h>

#define NN 50000
#define NE 1600000
#define DF 256
#define NBUCK 391   // ceil(NN/128); bucket = dst >> 7

typedef unsigned short ushortT;
typedef __attribute__((ext_vector_type(8))) short short8;
typedef __attribute__((ext_vector_type(4))) float floatx4;

__device__ __forceinline__ unsigned bf16rne(float f) {
    unsigned u = __float_as_uint(f);
    return (u + 0x7fffu + ((u >> 16) & 1u)) >> 16;
}

#define ASYNC16(gptr, ldsptr) \
    __builtin_amdgcn_global_load_lds((const __attribute__((address_space(1))) unsigned*)(gptr), \
                                     (__attribute__((address_space(3))) unsigned*)(ldsptr), 16, 0, 0)

// ---------------- CSR build via bucket binning ----------------

__global__ void k_zero(int* __restrict__ bcnt) {
    int i = blockIdx.x * 256 + threadIdx.x;
    if (i < NBUCK) bcnt[i] = 0;
}

__global__ __launch_bounds__(256)
void k_bhist(const int* __restrict__ dst, int* __restrict__ bcnt) {
    __shared__ int h[NBUCK];
    for (int i = threadIdx.x; i < NBUCK; i += 256) h[i] = 0;
    __syncthreads();
    int base = blockIdx.x * 4096;
#pragma unroll
    for (int i = 0; i < 16; ++i) {
        int e = base + i * 256 + threadIdx.x;
        if (e < NE) atomicAdd(&h[dst[e] >> 7], 1);
    }
    __syncthreads();
    for (int i = threadIdx.x; i < NBUCK; i += 256)
        if (h[i]) atomicAdd(&bcnt[i], h[i]);
}

__global__ void k_bscan(const int* __restrict__ bcnt, int* __restrict__ bbase,
                        int* __restrict__ cursor, int* __restrict__ row_ptr,
                        float* __restrict__ nrm) {
    __shared__ int s[512];
    int t = threadIdx.x;
    int v = (t < NBUCK) ? bcnt[t] : 0;
    s[t] = v; __syncthreads();
    for (int off = 1; off < 512; off <<= 1) {
        int x = (t >= off) ? s[t - off] : 0;
        __syncthreads();
        s[t] += x;
        __syncthreads();
    }
    if (t < NBUCK) { bbase[t] = s[t] - v; cursor[t] = s[t] - v; }
    if (t == 0) { bbase[NBUCK] = NE; row_ptr[NN] = NE; *nrm = 0.0f; }
}

__global__ __launch_bounds__(256)
void k_bin(const int* __restrict__ src, const int* __restrict__ dst,
           int* __restrict__ cursor, unsigned* __restrict__ rec) {
    __shared__ int h[NBUCK];
    __shared__ int gb[NBUCK];
    for (int i = threadIdx.x; i < NBUCK; i += 256) h[i] = 0;
    __syncthreads();
    const int base = blockIdx.x * 2048;
    int bk[8], rk[8];
    unsigned pk[8];
#pragma unroll
    for (int i = 0; i < 8; ++i) {
        int e = base + i * 256 + threadIdx.x;
        if (e < NE) {
            int d = dst[e];
            bk[i] = d >> 7;
            pk[i] = (unsigned)src[e] | ((unsigned)(d & 127) << 16);
            rk[i] = atomicAdd(&h[bk[i]], 1);
        } else bk[i] = -1;
    }
    __syncthreads();
    for (int i = threadIdx.x; i < NBUCK; i += 256) {
        int c = h[i];
        gb[i] = c ? atomicAdd(&cursor[i], c) : 0;
    }
    __syncthreads();
#pragma unroll
    for (int i = 0; i < 8; ++i)
        if (bk[i] >= 0) rec[gb[bk[i]] + rk[i]] = pk[i];
}

__global__ __launch_bounds__(256)
void k_csr(const unsigned* __restrict__ rec, const int* __restrict__ bbase,
           int* __restrict__ row_ptr, ushortT* __restrict__ csr) {
    __shared__ int cnt[128];
    __shared__ int cur[128];
    __shared__ int s[256];
    const int B = blockIdx.x, t = threadIdx.x;
    if (t < 128) cnt[t] = 0;
    __syncthreads();
    const int beg = bbase[B], end = bbase[B + 1];
    for (int p = beg + t; p < end; p += 256)
        atomicAdd(&cnt[(rec[p] >> 16) & 127], 1);
    __syncthreads();
    int v = (t < 128) ? cnt[t] : 0;
    s[t] = v; __syncthreads();
    for (int off = 1; off < 256; off <<= 1) {
        int x = (t >= off) ? s[t - off] : 0;
        __syncthreads();
        s[t] += x;
        __syncthreads();
    }
    if (t < 128) {
        int ex = s[t] - v;
        cur[t] = ex;
        int node = B * 128 + t;
        if (node < NN) row_ptr[node] = beg + ex;
    }
    __syncthreads();
    for (int p = beg + t; p < end; p += 256) {
        unsigned r = rec[p];
        int loc = atomicAdd(&cur[(r >> 16) & 127], 1);
        csr[beg + loc] = (ushortT)r;
    }
}

// ---------------- conversions ----------------

__global__ __launch_bounds__(256)
void k_cvt_emb(const float* __restrict__ emb, const int* __restrict__ gather,
               ushortT* __restrict__ out) {
    long long i = ((long long)blockIdx.x * 256 + threadIdx.x) * 8;
    int row = (int)(i >> 8);
    int col = (int)(i & 255);
    long long g = (long long)gather[row] * 256 + col;
    float4 v0 = *(const float4*)(emb + g);
    float4 v1 = *(const float4*)(emb + g + 4);
    uint4 o;
    o.x = bf16rne(v0.x) | (bf16rne(v0.y) << 16);
    o.y = bf16rne(v0.z) | (bf16rne(v0.w) << 16);
    o.z = bf16rne(v1.x) | (bf16rne(v1.y) << 16);
    o.w = bf16rne(v1.z) | (bf16rne(v1.w) << 16);
    *(uint4*)(out + i) = o;
}

__global__ __launch_bounds__(256)
void k_cvt_w(const float* __restrict__ Ws, const float* __restrict__ Wn,
             ushortT* __restrict__ Wt) {
    int idx = blockIdx.x * 256 + threadIdx.x;
    int n = idx >> 9;
    int k = idx & 511;
    float v = (k < 256) ? Ws[k * 256 + n] : Wn[(k - 256) * 256 + n];
    Wt[idx] = (ushortT)bf16rne(v);
}

// ---------------- neighbor mean aggregation (bf16, MLP=8) ----------------
// one wave per node; wave-halves take even/odd edges; 8 gathers in flight/half

__global__ __launch_bounds__(256)
void k_agg(const ushortT* __restrict__ feat, const int* __restrict__ row_ptr,
           const ushortT* __restrict__ csr, ushortT* __restrict__ out) {
    int node = blockIdx.x * 4 + (threadIdx.x >> 6);
    int lane = threadIdx.x & 63;
    int half = lane >> 5;
    int l5 = lane & 31;
    if (node >= NN) return;
    int beg = row_ptr[node], end = row_ptr[node + 1];

    float s[8] = {0.f, 0.f, 0.f, 0.f, 0.f, 0.f, 0.f, 0.f};
    int p = beg + half;

#define ACCUM(q) do { \
        s[0] += __uint_as_float(q.x << 16); \
        s[1] += __uint_as_float(q.x & 0xffff0000u); \
        s[2] += __uint_as_float(q.y << 16); \
        s[3] += __uint_as_float(q.y & 0xffff0000u); \
        s[4] += __uint_as_float(q.z << 16); \
        s[5] += __uint_as_float(q.z & 0xffff0000u); \
        s[6] += __uint_as_float(q.w << 16); \
        s[7] += __uint_as_float(q.w & 0xffff0000u); \
    } while (0)

    // main: 16 edges per wave iteration (8 in flight per half)
    for (; p + 14 < end; p += 16) {
        uint4 q[8];
#pragma unroll
        for (int i = 0; i < 8; ++i) {
            long long r = (long long)csr[p + 2 * i] * 256 + l5 * 8;
            q[i] = *(const uint4*)(feat + r);
        }
#pragma unroll
        for (int i = 0; i < 8; ++i) ACCUM(q[i]);
    }
    for (; p + 6 < end; p += 8) {
        uint4 q[4];
#pragma unroll
        for (int i = 0; i < 4; ++i) {
            long long r = (long long)csr[p + 2 * i] * 256 + l5 * 8;
            q[i] = *(const uint4*)(feat + r);
        }
#pragma unroll
        for (int i = 0; i < 4; ++i) ACCUM(q[i]);
    }
    for (; p < end; p += 2) {
        long long r0 = (long long)csr[p] * 256 + l5 * 8;
        uint4 a = *(const uint4*)(feat + r0);
        ACCUM(a);
    }
#undef ACCUM

#pragma unroll
    for (int k = 0; k < 8; ++k) s[k] += __shfl_down(s[k], 32);

    if (half == 0) {
        float inv = 1.0f / fmaxf((float)(end - beg), 1.0f);
        uint4 o;
        o.x = bf16rne(s[0] * inv) | (bf16rne(s[1] * inv) << 16);
        o.y = bf16rne(s[2] * inv) | (bf16rne(s[3] * inv) << 16);
        o.z = bf16rne(s[4] * inv) | (bf16rne(s[5] * inv) << 16);
        o.w = bf16rne(s[6] * inv) | (bf16rne(s[7] * inv) << 16);
        *(uint4*)(out + (long long)node * 256 + l5 * 8) = o;
    }
}

// ---------------- fused dual GEMM, bf16 MFMA ----------------

template<int RELU, int NORM>
__global__ __launch_bounds__(256, 3)
void k_gemm(const ushortT* __restrict__ Aself, const ushortT* __restrict__ Aneigh,
            const ushortT* __restrict__ Wt, const float* __restrict__ bias,
            ushortT* __restrict__ Cb, float* __restrict__ Cf, float* __restrict__ norm_acc) {
    __shared__ ushortT As[4096];
    __shared__ ushortT Bs[4096];
    __shared__ float red[4];

    const int t = threadIdx.x;
    const int w = t >> 6;
    const int lane = t & 63;
    const int m0 = blockIdx.x * 128;
    const int n0 = blockIdx.y * 128;

    const int r0 = t >> 2;
    const int cu = (t & 3) * 8;

    const long long gA0 = (long long)min(m0 + r0, NN - 1) * 256;
    const long long gA1 = (long long)min(m0 + r0 + 64, NN - 1) * 256;
    const long long gB0 = (long long)(n0 + r0) * 512;
    const long long gB1 = (long long)(n0 + r0 + 64) * 512;

    const unsigned lds0 = w * 512;
    const unsigned lds1 = 2048 + w * 512;

    const int wm = w & 1, wn = w >> 1;
    const int fm = lane & 15;
    const int fk = (lane >> 4) * 8;

    floatx4 acc[4][4];
#pragma unroll
    for (int i = 0; i < 4; ++i)
#pragma unroll
        for (int j = 0; j < 4; ++j) acc[i][j] = (floatx4){0.f, 0.f, 0.f, 0.f};

    for (int kt = 0; kt < 512; kt += 32) {
        const ushortT* Ab; int kc;
        if (kt < 256) { Ab = Aself; kc = kt; } else { Ab = Aneigh; kc = kt - 256; }

        __syncthreads();
        ASYNC16(Ab + gA0 + kc + cu, As + lds0);
        ASYNC16(Ab + gA1 + kc + cu, As + lds1);
        ASYNC16(Wt + gB0 + kt + cu, Bs + lds0);
        ASYNC16(Wt + gB1 + kt + cu, Bs + lds1);
        __syncthreads();

        short8 af[4], bf[4];
#pragma unroll
        for (int i = 0; i < 4; ++i)
            af[i] = *(const short8*)&As[(wm * 64 + i * 16 + fm) * 32 + fk];
#pragma unroll
        for (int j = 0; j < 4; ++j)
            bf[j] = *(const short8*)&Bs[(wn * 64 + j * 16 + fm) * 32 + fk];
#pragma unroll
        for (int i = 0; i < 4; ++i)
#pragma unroll
            for (int j = 0; j < 4; ++j)
                acc[i][j] = __builtin_amdgcn_mfma_f32_16x16x32_bf16(af[i], bf[j], acc[i][j], 0, 0, 0);
    }

    float bj[4];
#pragma unroll
    for (int j = 0; j < 4; ++j) bj[j] = bias[n0 + wn * 64 + j * 16 + fm];

    float sumsq = 0.0f;
#pragma unroll
    for (int i = 0; i < 4; ++i) {
#pragma unroll
        for (int r = 0; r < 4; ++r) {
            const int row = m0 + wm * 64 + i * 16 + (lane >> 4) * 4 + r;
            if (row < NN) {
#pragma unroll
                for (int j = 0; j < 4; ++j) {
                    const int col = n0 + wn * 64 + j * 16 + fm;
                    float v = acc[i][j][r] + bj[j];
                    if (RELU) v = fmaxf(v, 0.0f);
                    if (NORM) {
                        Cf[(long long)row * 256 + col] = v;
                        sumsq += v * v;
                    } else {
                        Cb[(long long)row * 256 + col] = (ushortT)bf16rne(v);
                    }
                }
            }
        }
    }

    if (NORM) {
#pragma unroll
        for (int off = 32; off > 0; off >>= 1) sumsq += __shfl_down(sumsq, off);
        if (lane == 0) red[w] = sumsq;
        __syncthreads();
        if (t == 0) atomicAdd(norm_acc, red[0] + red[1] + red[2] + red[3]);
    }
}

__global__ void k_scale(float* __restrict__ out, const float* __restrict__ nrm) {
    const float s = 1.0f / sqrtf(*nrm);
    long long i = ((long long)blockIdx.x * 256 + threadIdx.x) * 4;
    float4 v = *(float4*)&out[i];
    v.x *= s; v.y *= s; v.z *= s; v.w *= s;
    *(float4*)&out[i] = v;
}

// ---------------- launch ----------------

extern "C" void kernel_launch(void* const* d_in, const int* in_sizes, int n_in,
                              void* d_out, int out_size, void* d_ws, size_t ws_size,
                              hipStream_t stream) {
    const int*   input_nodes = (const int*)d_in[0];
    const int*   esrc = (const int*)d_in[1];
    const int*   edst = (const int*)d_in[2];
    const float* emb  = (const float*)d_in[3];
    const float* Ws0  = (const float*)d_in[4];
    const float* Wn0  = (const float*)d_in[5];
    const float* b0   = (const float*)d_in[6];
    const float* Ws1  = (const float*)d_in[7];
    const float* Wn1  = (const float*)d_in[8];
    const float* b1   = (const float*)d_in[9];
    float* out = (float*)d_out;

    char* base = (char*)d_ws;
    ushortT*  embb    = (ushortT*) (base);                  // 25,600,000
    ushortT*  h1b     = (ushortT*) (base + 25600000);       // 25,600,000
    ushortT*  hnb     = (ushortT*) (base + 51200000);       // 25,600,000
    unsigned* rec     = (unsigned*)(base + 76800000);       //  6,400,000
    ushortT*  csr     = (ushortT*) (base + 83200000);       //  3,200,000
    ushortT*  Wt0     = (ushortT*) (base + 86400000);       //    262,144
    ushortT*  Wt1     = (ushortT*) (base + 86662144);       //    262,144
    int*      row_ptr = (int*)     (base + 86924288);       //    200,016
    int*      bcnt    = (int*)     (base + 87124304);       //      1,600
    int*      bbase   = (int*)     (base + 87125904);       //      1,600
    int*      cursor  = (int*)     (base + 87127504);       //      1,600
    float*    nrm     = (float*)   (base + 87129104);       //          4

    k_zero  <<<2,     256, 0, stream>>>(bcnt);
    k_bhist <<<391,   256, 0, stream>>>(edst, bcnt);
    k_bscan <<<1,     512, 0, stream>>>(bcnt, bbase, cursor, row_ptr, nrm);
    k_bin   <<<782,   256, 0, stream>>>(esrc, edst, cursor, rec);
    k_csr   <<<NBUCK, 256, 0, stream>>>(rec, bbase, row_ptr, csr);

    k_cvt_emb<<<NN * DF / 8 / 256, 256, 0, stream>>>(emb, input_nodes, embb);
    k_cvt_w  <<<512, 256, 0, stream>>>(Ws0, Wn0, Wt0);
    k_cvt_w  <<<512, 256, 0, stream>>>(Ws1, Wn1, Wt1);

    dim3 gg((NN + 127) / 128, 2);

    // layer 0
    k_agg<<<NN / 4, 256, 0, stream>>>(embb, row_ptr, csr, hnb);
    k_gemm<1, 0><<<gg, 256, 0, stream>>>(embb, hnb, Wt0, b0, h1b, nullptr, nullptr);

    // layer 1
    k_agg<<<NN / 4, 256, 0, stream>>>(h1b, row_ptr, csr, hnb);
    k_gemm<0, 1><<<gg, 256, 0, stream>>>(h1b, hnb, Wt1, b1, nullptr, out, nrm);

    k_scale<<<NN * DF / 4 / 256, 256, 0, stream>>>(out, nrm);
}